// Round 7
// baseline (5411.198 us; speedup 1.0000x reference)
//
#include <hip/hip_runtime.h>
#include <math.h>

#define SS 512
#define BB 32
#define HH 256
#define TT 11
#define NEGV (-1000.0f)

typedef unsigned long long ull;

// ---------------- workspace layout (bytes) ----------------
static const size_t OFF_H0    = 0;                          // 33,554,432 : h0 f32 [32*512][512]
static const size_t OFF_H1    = 33554432ull;                // 33,554,432 : h1 f32
static const size_t OFF_FEATS = 67108864ull;                // 720,896    : feats [B][S][11]
static const size_t OFF_HMB   = 67829760ull;                // 262,144    : tagged h mailbox [2][2][32][256] u64
// total ~68 MB

// fast transcendentals (1-2 ulp; outputs compared in bf16 w/ large threshold)
__device__ __forceinline__ float fsig(float x) {
  return __builtin_amdgcn_rcpf(1.f + __expf(-x));
}
__device__ __forceinline__ float ftanh(float x) {
  return 1.f - 2.f * __builtin_amdgcn_rcpf(__expf(2.f * x) + 1.f);
}

// raw barrier: drains LDS ops only (NO vmcnt(0) drain)
__device__ __forceinline__ void block_sync_lds() {
  asm volatile("s_waitcnt lgkmcnt(0)\n\ts_barrier" ::: "memory");
}

// ---------------- fused recurrent scans ----------------
// Proven R14 relay core (grid (8,16,2), 4 waves, lane-half k-split, 1 barrier/
// step, tagged parity mailbox, agent atomics, poll-skip s==0, TAGOFF) PLUS the
// input projection fused into the ~70%-idle wait slack:
//   xs(t+1) = wih . input(t+1) + bias depends only on launch-complete data,
//   so it's computed OFF the relay critical path: input vector prefetched to
//   regs 2 steps ahead -> staged to LDS pre-barrier -> wih dot AFTER the
//   h-store, overlapping the next step's producer-wait. Same lane-row/k-half/
//   shfl-gather structure as the whh matvec. Full-f32 FMA (more accurate than
//   the split-bf16 MFMA proj it replaces).
// scan0: input = emb[x[b][t]] (256-dim); scan1: input = h0[b][t] (512-dim).

template<int TAGOFF>
__global__ __launch_bounds__(256, 1)
void scan0_fused(const int* __restrict__ x, const float* __restrict__ emb,
                 const float* __restrict__ wihf, const float* __restrict__ wihb,
                 const float* __restrict__ bf_, const float* __restrict__ bb_,
                 const float* __restrict__ whhf, const float* __restrict__ whhb,
                 ull* __restrict__ hmb, float* __restrict__ hout)
{
  int tid  = threadIdx.x;
  int w    = tid >> 6;
  int lane = tid & 63;
  int cg   = blockIdx.x;        // cell group 0..7
  int bg   = blockIdx.y;        // batch pair 0..15
  int dir  = blockIdx.z;
  const float* whh  = dir ? whhb : whhf;
  const float* wih  = dir ? wihb : wihf;
  const float* bias = dir ? bb_ : bf_;
  size_t dbase = (size_t)dir * 16384;

  __shared__ float h_sh[2][2][256];   // [parity][batch][cell]
  __shared__ float xesh[2][2][256];   // [buf][batch][k] staged input vectors

  int r    = lane & 31;
  int ks   = lane >> 5;
  int g    = r >> 3;
  int c7   = r & 7;
  int cell = cg * 32 + w * 8 + c7;
  int grow = g * 256 + cell;

  float4 wreg[32], ureg[32];
  {
    const float* wp = whh + (size_t)grow * 256 + ks * 128;
    const float* up = wih + (size_t)grow * 256 + ks * 128;
    #pragma unroll
    for (int j = 0; j < 32; j++) {
      wreg[j] = *(const float4*)(wp + j * 4);
      ureg[j] = *(const float4*)(up + j * 4);
    }
  }

  int b0  = bg * 2;
  int col = tid & 255;
  bool ul = (r < 8);
  int ub  = b0 + ks;
  float bv[4] = {0.f, 0.f, 0.f, 0.f};
  if (ul) {
    #pragma unroll
    for (int gg = 0; gg < 4; gg++) bv[gg] = bias[gg * 256 + cell];
  }

  // staging role: threads 0..127 carry one float4 of the 2x256 input
  int  sbb = (tid >> 6) & 1;
  int  sqo = (tid & 63) * 4;
  bool stg = (tid < 128);
  float4 pin = {0.f, 0.f, 0.f, 0.f};

  // prologue: stage xe(t_of(0)) -> xesh[1], dot -> xf(t0)
  {
    int t0 = dir ? (SS - 1) : 0;
    if (stg) {
      int xi = x[(b0 + sbb) * SS + t0];
      pin = *(const float4*)(emb + (size_t)xi * HH + sqo);
      *(float4*)&xesh[1][sbb][sqo] = pin;
    }
  }
  block_sync_lds();
  float xf[4];
  {
    float ua0 = 0.f, ua1 = 0.f;
    const float* e0 = &xesh[1][0][ks * 128];
    const float* e1 = &xesh[1][1][ks * 128];
    #pragma unroll
    for (int j = 0; j < 32; j++) {
      float4 v0 = *(const float4*)(e0 + j * 4);
      float4 v1 = *(const float4*)(e1 + j * 4);
      float4 uv = ureg[j];
      ua0 += uv.x * v0.x + uv.y * v0.y + uv.z * v0.z + uv.w * v0.w;
      ua1 += uv.x * v1.x + uv.y * v1.y + uv.z * v1.z + uv.w * v1.w;
    }
    ua0 += __shfl_xor(ua0, 32, 64);
    ua1 += __shfl_xor(ua1, 32, 64);
    float vu = ks ? ua1 : ua0;
    #pragma unroll
    for (int gg = 0; gg < 4; gg++) {
      float t = __shfl(vu, (lane & 32) + gg * 8 + (lane & 7), 64);
      xf[gg] = t + bv[gg];
    }
  }
  // prefetch xe(t_of(1))
  if (stg) {
    int t1 = dir ? (SS - 2) : 1;
    int xi = x[(b0 + sbb) * SS + t1];
    pin = *(const float4*)(emb + (size_t)xi * HH + sqo);
  }

  float cst = 0.f;
  for (int s = 0; s < SS; ++s) {
    int p = s & 1;
    size_t mb = dbase + (size_t)(p * 32 + b0) * 256 + col;
    ull rv0 = 0, rv1 = 0;
    if (s > 0) {
      unsigned st = (unsigned)(TAGOFF + s);
      for (;;) {
        rv0 = __hip_atomic_load(hmb + mb,       __ATOMIC_RELAXED, __HIP_MEMORY_SCOPE_AGENT);
        rv1 = __hip_atomic_load(hmb + mb + 256, __ATOMIC_RELAXED, __HIP_MEMORY_SCOPE_AGENT);
        unsigned m = (((unsigned)(rv0 >> 32)) ^ st) | (((unsigned)(rv1 >> 32)) ^ st);
        if (__all(m == 0u)) break;
      }
    }
    h_sh[p][0][col] = __uint_as_float((unsigned)rv0);
    h_sh[p][1][col] = __uint_as_float((unsigned)rv1);
    if (stg && s + 1 < SS) *(float4*)&xesh[p][sbb][sqo] = pin;
    block_sync_lds();

    // critical: whh matvec
    float acc0 = 0.f, acc1 = 0.f;
    const float* hb0 = &h_sh[p][0][ks * 128];
    const float* hb1 = &h_sh[p][1][ks * 128];
    #pragma unroll
    for (int j = 0; j < 32; j++) {
      float4 hv0 = *(const float4*)(hb0 + j * 4);
      float4 hv1 = *(const float4*)(hb1 + j * 4);
      float4 wv  = wreg[j];
      acc0 += wv.x * hv0.x + wv.y * hv0.y + wv.z * hv0.z + wv.w * hv0.w;
      acc1 += wv.x * hv1.x + wv.y * hv1.y + wv.z * hv1.z + wv.w * hv1.w;
    }
    acc0 += __shfl_xor(acc0, 32, 64);
    acc1 += __shfl_xor(acc1, 32, 64);
    float v = ks ? acc1 : acc0;
    float gv[4];
    #pragma unroll
    for (int gg = 0; gg < 4; gg++)
      gv[gg] = __shfl(v, (lane & 32) + gg * 8 + (lane & 7), 64);

    if (ul) {
      float ig = fsig(gv[0] + xf[0]);
      float fg = fsig(gv[1] + xf[1]);
      float gt = ftanh(gv[2] + xf[2]);
      float og = fsig(gv[3] + xf[3]);
      cst = fg * cst + ig * gt;
      float hv = og * ftanh(cst);
      ull tagw = ((ull)(unsigned)(TAGOFF + s + 1) << 32) | (ull)__float_as_uint(hv);
      size_t mo = dbase + (size_t)((((s + 1) & 1) * 32 + ub)) * 256 + cell;
      __hip_atomic_store(hmb + mo, tagw,
                         __ATOMIC_RELAXED, __HIP_MEMORY_SCOPE_AGENT);
      int tcur = dir ? (SS - 1 - s) : s;
      hout[((size_t)(ub * SS + tcur)) * 512 + dir * 256 + cell] = hv;
    }

    // off-path: xs(t_of(s+1)) from xesh[p] -> xf for next step
    if (s + 1 < SS) {
      float ua0 = 0.f, ua1 = 0.f;
      const float* e0 = &xesh[p][0][ks * 128];
      const float* e1 = &xesh[p][1][ks * 128];
      #pragma unroll
      for (int j = 0; j < 32; j++) {
        float4 v0 = *(const float4*)(e0 + j * 4);
        float4 v1 = *(const float4*)(e1 + j * 4);
        float4 uv = ureg[j];
        ua0 += uv.x * v0.x + uv.y * v0.y + uv.z * v0.z + uv.w * v0.w;
        ua1 += uv.x * v1.x + uv.y * v1.y + uv.z * v1.z + uv.w * v1.w;
      }
      ua0 += __shfl_xor(ua0, 32, 64);
      ua1 += __shfl_xor(ua1, 32, 64);
      float vu = ks ? ua1 : ua0;
      #pragma unroll
      for (int gg = 0; gg < 4; gg++) {
        float t = __shfl(vu, (lane & 32) + gg * 8 + (lane & 7), 64);
        if (ul) xf[gg] = t + bv[gg];
      }
      // prefetch xe(t_of(s+2))
      if (stg && s + 2 < SS) {
        int tn2 = dir ? (SS - 3 - s) : (s + 2);
        int xi = x[(b0 + sbb) * SS + tn2];
        pin = *(const float4*)(emb + (size_t)xi * HH + sqo);
      }
    }
  }
}

template<int TAGOFF>
__global__ __launch_bounds__(256, 1)
void scan1_fused(const float* __restrict__ h0,
                 const float* __restrict__ wihf, const float* __restrict__ wihb,
                 const float* __restrict__ bf_, const float* __restrict__ bb_,
                 const float* __restrict__ whhf, const float* __restrict__ whhb,
                 ull* __restrict__ hmb, float* __restrict__ hout)
{
  int tid  = threadIdx.x;
  int w    = tid >> 6;
  int lane = tid & 63;
  int cg   = blockIdx.x;
  int bg   = blockIdx.y;
  int dir  = blockIdx.z;
  const float* whh  = dir ? whhb : whhf;
  const float* wih  = dir ? wihb : wihf;
  const float* bias = dir ? bb_ : bf_;
  size_t dbase = (size_t)dir * 16384;

  __shared__ float h_sh[2][2][256];   // [parity][batch][cell]
  __shared__ float h0sh[2][2][512];   // [buf][batch][k] staged h0 rows

  int r    = lane & 31;
  int ks   = lane >> 5;
  int g    = r >> 3;
  int c7   = r & 7;
  int cell = cg * 32 + w * 8 + c7;
  int grow = g * 256 + cell;

  float4 wreg[32];    // whh row-half (128 k)
  float4 ureg[64];    // wih1 row-half (256 k)
  {
    const float* wp = whh + (size_t)grow * 256 + ks * 128;
    #pragma unroll
    for (int j = 0; j < 32; j++) wreg[j] = *(const float4*)(wp + j * 4);
    const float* up = wih + (size_t)grow * 512 + ks * 256;
    #pragma unroll
    for (int j = 0; j < 64; j++) ureg[j] = *(const float4*)(up + j * 4);
  }

  int b0  = bg * 2;
  int col = tid & 255;
  bool ul = (r < 8);
  int ub  = b0 + ks;
  float bv[4] = {0.f, 0.f, 0.f, 0.f};
  if (ul) {
    #pragma unroll
    for (int gg = 0; gg < 4; gg++) bv[gg] = bias[gg * 256 + cell];
  }

  // staging: all 256 threads carry one float4 of the 2x512 input
  int sbb = tid >> 7;
  int sqo = (tid & 127) * 4;
  float4 pin;

  // prologue: stage h0(t_of(0)) -> h0sh[1], dot -> xf(t0)
  {
    int t0 = dir ? (SS - 1) : 0;
    pin = *(const float4*)(h0 + ((size_t)((b0 + sbb) * SS + t0)) * 512 + sqo);
    *(float4*)&h0sh[1][sbb][sqo] = pin;
  }
  block_sync_lds();
  float xf[4];
  {
    float ua0 = 0.f, ua1 = 0.f;
    const float* e0 = &h0sh[1][0][ks * 256];
    const float* e1 = &h0sh[1][1][ks * 256];
    #pragma unroll
    for (int j = 0; j < 64; j++) {
      float4 v0 = *(const float4*)(e0 + j * 4);
      float4 v1 = *(const float4*)(e1 + j * 4);
      float4 uv = ureg[j];
      ua0 += uv.x * v0.x + uv.y * v0.y + uv.z * v0.z + uv.w * v0.w;
      ua1 += uv.x * v1.x + uv.y * v1.y + uv.z * v1.z + uv.w * v1.w;
    }
    ua0 += __shfl_xor(ua0, 32, 64);
    ua1 += __shfl_xor(ua1, 32, 64);
    float vu = ks ? ua1 : ua0;
    #pragma unroll
    for (int gg = 0; gg < 4; gg++) {
      float t = __shfl(vu, (lane & 32) + gg * 8 + (lane & 7), 64);
      xf[gg] = t + bv[gg];
    }
  }
  // prefetch h0(t_of(1))
  {
    int t1 = dir ? (SS - 2) : 1;
    pin = *(const float4*)(h0 + ((size_t)((b0 + sbb) * SS + t1)) * 512 + sqo);
  }

  float cst = 0.f;
  for (int s = 0; s < SS; ++s) {
    int p = s & 1;
    size_t mb = dbase + (size_t)(p * 32 + b0) * 256 + col;
    ull rv0 = 0, rv1 = 0;
    if (s > 0) {
      unsigned st = (unsigned)(TAGOFF + s);
      for (;;) {
        rv0 = __hip_atomic_load(hmb + mb,       __ATOMIC_RELAXED, __HIP_MEMORY_SCOPE_AGENT);
        rv1 = __hip_atomic_load(hmb + mb + 256, __ATOMIC_RELAXED, __HIP_MEMORY_SCOPE_AGENT);
        unsigned m = (((unsigned)(rv0 >> 32)) ^ st) | (((unsigned)(rv1 >> 32)) ^ st);
        if (__all(m == 0u)) break;
      }
    }
    h_sh[p][0][col] = __uint_as_float((unsigned)rv0);
    h_sh[p][1][col] = __uint_as_float((unsigned)rv1);
    if (s + 1 < SS) *(float4*)&h0sh[p][sbb][sqo] = pin;
    block_sync_lds();

    // critical: whh matvec
    float acc0 = 0.f, acc1 = 0.f;
    const float* hb0 = &h_sh[p][0][ks * 128];
    const float* hb1 = &h_sh[p][1][ks * 128];
    #pragma unroll
    for (int j = 0; j < 32; j++) {
      float4 hv0 = *(const float4*)(hb0 + j * 4);
      float4 hv1 = *(const float4*)(hb1 + j * 4);
      float4 wv  = wreg[j];
      acc0 += wv.x * hv0.x + wv.y * hv0.y + wv.z * hv0.z + wv.w * hv0.w;
      acc1 += wv.x * hv1.x + wv.y * hv1.y + wv.z * hv1.z + wv.w * hv1.w;
    }
    acc0 += __shfl_xor(acc0, 32, 64);
    acc1 += __shfl_xor(acc1, 32, 64);
    float v = ks ? acc1 : acc0;
    float gv[4];
    #pragma unroll
    for (int gg = 0; gg < 4; gg++)
      gv[gg] = __shfl(v, (lane & 32) + gg * 8 + (lane & 7), 64);

    if (ul) {
      float ig = fsig(gv[0] + xf[0]);
      float fg = fsig(gv[1] + xf[1]);
      float gt = ftanh(gv[2] + xf[2]);
      float og = fsig(gv[3] + xf[3]);
      cst = fg * cst + ig * gt;
      float hv = og * ftanh(cst);
      ull tagw = ((ull)(unsigned)(TAGOFF + s + 1) << 32) | (ull)__float_as_uint(hv);
      size_t mo = dbase + (size_t)((((s + 1) & 1) * 32 + ub)) * 256 + cell;
      __hip_atomic_store(hmb + mo, tagw,
                         __ATOMIC_RELAXED, __HIP_MEMORY_SCOPE_AGENT);
      int tcur = dir ? (SS - 1 - s) : s;
      hout[((size_t)(ub * SS + tcur)) * 512 + dir * 256 + cell] = hv;
    }

    // off-path: xs(t_of(s+1)) from h0sh[p]
    if (s + 1 < SS) {
      float ua0 = 0.f, ua1 = 0.f;
      const float* e0 = &h0sh[p][0][ks * 256];
      const float* e1 = &h0sh[p][1][ks * 256];
      #pragma unroll
      for (int j = 0; j < 64; j++) {
        float4 v0 = *(const float4*)(e0 + j * 4);
        float4 v1 = *(const float4*)(e1 + j * 4);
        float4 uv = ureg[j];
        ua0 += uv.x * v0.x + uv.y * v0.y + uv.z * v0.z + uv.w * v0.w;
        ua1 += uv.x * v1.x + uv.y * v1.y + uv.z * v1.z + uv.w * v1.w;
      }
      ua0 += __shfl_xor(ua0, 32, 64);
      ua1 += __shfl_xor(ua1, 32, 64);
      float vu = ks ? ua1 : ua0;
      #pragma unroll
      for (int gg = 0; gg < 4; gg++) {
        float t = __shfl(vu, (lane & 32) + gg * 8 + (lane & 7), 64);
        if (ul) xf[gg] = t + bv[gg];
      }
      // prefetch h0(t_of(s+2))
      if (s + 2 < SS) {
        int tn2 = dir ? (SS - 3 - s) : (s + 2);
        pin = *(const float4*)(h0 + ((size_t)((b0 + sbb) * SS + tn2)) * 512 + sqo);
      }
    }
  }
}

// ---------------- emission features ----------------
__global__ void feats_kernel(const float* __restrict__ h1, const float* __restrict__ wout,
                             const float* __restrict__ bout, float* __restrict__ feats) {
  int bs = blockIdx.x;
  int lane = threadIdx.x;
  const float* hp = h1 + (size_t)bs * 512;
  float hv[8];
  #pragma unroll
  for (int i = 0; i < 8; i++) hv[i] = hp[lane + i * 64];
  #pragma unroll
  for (int t = 0; t < TT; t++) {
    const float* wp = wout + t * 512;
    float p = 0.f;
    #pragma unroll
    for (int i = 0; i < 8; i++) p += hv[i] * wp[lane + i * 64];
    #pragma unroll
    for (int off = 32; off >= 1; off >>= 1) p += __shfl_down(p, off, 64);
    if (lane == 0) feats[(size_t)bs * TT + t] = p + bout[t];
  }
}

// ---------------- Viterbi decode ----------------
__global__ void viterbi_kernel(const float* __restrict__ feats, const float* __restrict__ trans,
                               float* __restrict__ out) {
  int b = blockIdx.x;
  int lane = threadIdx.x;
  __shared__ float tr[121];
  __shared__ float fch[32 * TT];
  __shared__ unsigned char bp[SS][12];
  __shared__ unsigned char path[SS];
  for (int i = lane; i < 121; i += 64) tr[i] = trans[i];
  __syncthreads();
  int ln = lane < TT ? lane : (TT - 1);
  float trr[TT];
  #pragma unroll
  for (int p = 0; p < TT; p++) trr[p] = tr[ln * TT + p];
  float fv = (lane == 9) ? 0.f : NEGV;   // START = 9
  const float* fb = feats + (size_t)b * SS * TT;

  for (int s = 0; s < SS; s++) {
    if ((s & 31) == 0) {
      __syncthreads();
      for (int i = lane; i < 32 * TT; i += 64) fch[i] = fb[s * TT + i];
      __syncthreads();
    }
    float best = -3.0e38f; int arg = 0;
    #pragma unroll
    for (int p = 0; p < TT; p++) {
      float v = __shfl(fv, p, 64) + trr[p];
      if (v > best) { best = v; arg = p; }   // strict > keeps FIRST max (numpy argmax)
    }
    if (lane < TT) bp[s][lane] = (unsigned char)arg;
    fv = best + fch[(s & 31) * TT + ln];
  }
  float term = fv + tr[10 * TT + ln];        // STOP = 10
  float best = -3.0e38f; int arg = 0;
  #pragma unroll
  for (int p = 0; p < TT; p++) {
    float v = __shfl(term, p, 64);
    if (v > best) { best = v; arg = p; }
  }
  __syncthreads();
  if (lane == 0) {
    out[b] = best;
    int tg = arg;
    path[SS - 1] = (unsigned char)tg;
    for (int s = SS - 1; s >= 1; s--) {
      tg = bp[s][tg];
      path[s - 1] = (unsigned char)tg;
    }
  }
  __syncthreads();
  for (int i = lane; i < SS; i += 64) out[32 + b * SS + i] = (float)path[i];
}

// ---------------- launcher ----------------
extern "C" void kernel_launch(void* const* d_in, const int* in_sizes, int n_in,
                              void* d_out, int out_size, void* d_ws, size_t ws_size,
                              hipStream_t stream) {
  const int*   x     = (const int*)d_in[0];
  const float* emb   = (const float*)d_in[2];
  const float* wih0f = (const float*)d_in[3];
  const float* whh0f = (const float*)d_in[4];
  const float* b0f   = (const float*)d_in[5];
  const float* wih0b = (const float*)d_in[6];
  const float* whh0b = (const float*)d_in[7];
  const float* b0b   = (const float*)d_in[8];
  const float* wih1f = (const float*)d_in[9];
  const float* whh1f = (const float*)d_in[10];
  const float* b1f   = (const float*)d_in[11];
  const float* wih1b = (const float*)d_in[12];
  const float* whh1b = (const float*)d_in[13];
  const float* b1b   = (const float*)d_in[14];
  const float* wout  = (const float*)d_in[15];
  const float* bout  = (const float*)d_in[16];
  const float* trans = (const float*)d_in[17];

  char* ws = (char*)d_ws;
  float* h0    = (float*)(ws + OFF_H0);
  float* h1    = (float*)(ws + OFF_H1);
  float* feats = (float*)(ws + OFF_FEATS);
  ull*   hmb   = (ull*)(ws + OFF_HMB);
  float* outp  = (float*)d_out;

  hipMemsetAsync(hmb, 0, 262144, stream);   // tag 0 == initial h(0) = 0, both parities

  // layer 0: fused emb-gather + wih0 projection + recurrent scan
  scan0_fused<0><<<dim3(8, 16, 2), 256, 0, stream>>>(
      x, emb, wih0f, wih0b, b0f, b0b, whh0f, whh0b, hmb, h0);

  // layer 1: fused wih1 projection + recurrent scan
  // (no memset: tags 1000+s can never match scan0's residual tags <= 512)
  scan1_fused<1000><<<dim3(8, 16, 2), 256, 0, stream>>>(
      h0, wih1f, wih1b, b1f, b1b, whh1f, whh1b, hmb, h1);

  feats_kernel<<<BB * SS, 64, 0, stream>>>(h1, wout, bout, feats);
  viterbi_kernel<<<BB, 64, 0, stream>>>(feats, trans, outp);
}